// Round 9
// baseline (433.860 us; speedup 1.0000x reference)
//
#include <hip/hip_runtime.h>
#include <hip/hip_bf16.h>
#include <hip/hip_fp16.h>

#define NCLS 40

typedef __attribute__((ext_vector_type(8))) _Float16 half8;
typedef __attribute__((ext_vector_type(2))) _Float16 half2h;
union H2U { half2h h; unsigned u; };

// ---------------- CSR build: bucketed counting sort ----------------
#define EPB 16384     // edges per level-1 block
#define MAXB1 128     // max level-1 blocks (E <= MAXB1*EPB)
#define MAXNB 104     // max buckets (N <= MAXNB*1024)

__global__ void bucket_hist(const int* __restrict__ dst, int E, int nb,
                            int* __restrict__ blockHist) {
    __shared__ int cnt[4][MAXNB];   // 4-way replicated to cut LDS-atomic collisions
    int t = threadIdx.x;  // 256
    for (int i = t; i < 4 * MAXNB; i += 256) cnt[i / MAXNB][i % MAXNB] = 0;
    __syncthreads();
    int bk = t & 3;
    int base = blockIdx.x * EPB;
    int end = min(base + EPB, E);
    for (int i = base + t; i < end; i += 256) atomicAdd(&cnt[bk][dst[i] >> 10], 1);
    __syncthreads();
    for (int i = t; i < nb; i += 256)
        blockHist[blockIdx.x * nb + i] = cnt[0][i] + cnt[1][i] + cnt[2][i] + cnt[3][i];
}

// also zeroes the 512-byte reduction scratch (replaces a memset dispatch)
__global__ void bucket_scan(const int* __restrict__ blockHist, int nB1, int nb,
                            int* __restrict__ blockBase, int* __restrict__ bucketOffs,
                            int* __restrict__ offs, int N, int E, int* __restrict__ red32) {
    __shared__ int h[MAXB1 * MAXNB];
    __shared__ int btot[MAXNB];
    __shared__ int boffs[MAXNB + 1];
    int t = threadIdx.x;  // 128
    if (t < 128) red32[t] = 0;
    int total = nB1 * nb;
    for (int i = t; i < total; i += 128) h[i] = blockHist[i];
    __syncthreads();
    for (int b = t; b < nb; b += 128) {
        int run = 0;
        for (int i = 0; i < nB1; ++i) { int v = h[i * nb + b]; h[i * nb + b] = run; run += v; }
        btot[b] = run;
    }
    __syncthreads();
    if (t == 0) {
        int run = 0;
        for (int b = 0; b < nb; ++b) { boffs[b] = run; run += btot[b]; }
        boffs[nb] = run;
    }
    __syncthreads();
    for (int b = t; b < nb; b += 128) {
        int bo = boffs[b];
        for (int i = 0; i < nB1; ++i) h[i * nb + b] += bo;
    }
    __syncthreads();
    for (int i = t; i < total; i += 128) blockBase[i] = h[i];
    for (int b = t; b <= nb; b += 128) bucketOffs[b] = boffs[b];
    if (t == 0) offs[N] = E;
}

__global__ void bucket_place(const int* __restrict__ src, const int* __restrict__ dst, int E,
                             int nb, const int* __restrict__ blockBase,
                             unsigned* __restrict__ tmp) {
    __shared__ int cur[MAXNB];
    int t = threadIdx.x;  // 256
    for (int i = t; i < nb; i += 256) cur[i] = blockBase[blockIdx.x * nb + i];
    __syncthreads();
    int base = blockIdx.x * EPB;
    int end = min(base + EPB, E);
    for (int i = base + t; i < end; i += 256) {
        int d = dst[i];
        int s = src[i];
        unsigned pack = ((unsigned)(d & 1023) << 17) | (unsigned)s;  // src < 2^17
        int pos = atomicAdd(&cur[d >> 10], 1);
        tmp[pos] = pack;
    }
}

__global__ __launch_bounds__(512) void bucket_finalize(const unsigned* __restrict__ tmp,
                                                       const int* __restrict__ bucketOffs,
                                                       int N, int* __restrict__ offs,
                                                       int* __restrict__ esrc) {
    __shared__ int cnt[1024];
    __shared__ int wsum[8];
    int b = blockIdx.x;
    int t = threadIdx.x;  // 512
    int bstart = bucketOffs[b], bend = bucketOffs[b + 1];
    cnt[t] = 0;
    cnt[t + 512] = 0;
    __syncthreads();
    for (int i = bstart + t; i < bend; i += 512) atomicAdd(&cnt[tmp[i] >> 17], 1);
    __syncthreads();
    int c0 = cnt[2 * t], c1 = cnt[2 * t + 1];
    int s = c0 + c1;
    int lane = t & 63, w = t >> 6;
    int ssc = s;
    for (int off = 1; off < 64; off <<= 1) {
        int v = __shfl_up(ssc, off, 64);
        if (lane >= off) ssc += v;
    }
    if (lane == 63) wsum[w] = ssc;
    __syncthreads();
    int wo = 0;
#pragma unroll
    for (int k = 0; k < 8; ++k)
        if (k < w) wo += wsum[k];
    int excl = (ssc - s) + wo + bstart;
    __syncthreads();
    int node0 = (b << 10) + 2 * t;
    if (node0 < N) offs[node0] = excl;
    if (node0 + 1 < N) offs[node0 + 1] = excl + c0;
    cnt[2 * t] = excl;
    cnt[2 * t + 1] = excl + c0;
    __syncthreads();
    for (int i = bstart + t; i < bend; i += 512) {
        unsigned p = tmp[i];
        int pos = atomicAdd(&cnt[p >> 17], 1);
        esrc[pos] = (int)(p & 0x1FFFFu);
    }
}

// ---------------- dense X[N,64] @ W[64,FO] via packed fdot2 -----------------
// wave per row (grid-stride). Lane holds col-pair (lane&31) of X packed fp16;
// readlane broadcast + v_dot2_f32_f16 against packed fp16 W column. 2 accs.
__global__ __launch_bounds__(256) void gemm_fdot(const void* __restrict__ X, int xHalf,
                                                 const float* __restrict__ W,
                                                 const float* __restrict__ bias,
                                                 void* __restrict__ out, int outHalf,
                                                 int N, int FO) {
    int lane = threadIdx.x & 63;
    int waveId = (blockIdx.x * blockDim.x + threadIdx.x) >> 6;
    int nWaves = (gridDim.x * blockDim.x) >> 6;
    int cl = lane < FO ? lane : 0;
    int p = lane & 31;

    H2U wh[32];
#pragma unroll
    for (int j = 0; j < 32; ++j)
        wh[j].h = half2h{(_Float16)W[(2 * j) * FO + cl], (_Float16)W[(2 * j + 1) * FO + cl]};
    float gb = 0.f;
    if (bias != nullptr && lane < FO) gb = bias[lane];

    const unsigned* Xh = (const unsigned*)X;
    const float2* Xf = (const float2*)X;
    float* outF = (float*)out;
    _Float16* outH = (_Float16*)out;

    auto loadX = [&](int row) -> H2U {
        H2U r; r.u = 0;
        if (row < N) {
            if (xHalf) r.u = Xh[(size_t)row * 32 + p];
            else {
                float2 f = Xf[(size_t)row * 32 + p];
                r.h = half2h{(_Float16)f.x, (_Float16)f.y};
            }
        }
        return r;
    };

    int row = waveId;
    H2U xp = loadX(row);
    for (; row < N; row += nWaves) {
        H2U nxt = loadX(row + nWaves);
        float y0 = gb, y1 = 0.f;
#pragma unroll
        for (int j2 = 0; j2 < 32; j2 += 2) {
            H2U r0, r1;
            r0.u = __builtin_amdgcn_readlane(xp.u, j2);
            r1.u = __builtin_amdgcn_readlane(xp.u, j2 + 1);
            y0 = __builtin_amdgcn_fdot2(r0.h, wh[j2].h, y0, false);
            y1 = __builtin_amdgcn_fdot2(r1.h, wh[j2 + 1].h, y1, false);
        }
        float y = y0 + y1;
        if (lane < FO) {
            if (outHalf) outH[(size_t)row * FO + lane] = (_Float16)y;
            else         outF[(size_t)row * FO + lane] = y;
        }
        xp = nxt;
    }
}

// ---------------- aggregation over fp16 rows [N,64] -------------------------
// one wave/node: 8 edge slots x 8 col-octets. Packed v_pk_add_f16 accumulate
// (2 independent accs), fp32 cross-sub shuffle reduce, bias/relu, fp16 out.
__global__ void agg64h_kernel(const _Float16* __restrict__ t, const int* __restrict__ offs,
                              const int* __restrict__ esrc, const float* __restrict__ bias,
                              _Float16* __restrict__ out, int N, int doRelu) {
    int gid = blockIdx.x * blockDim.x + threadIdx.x;
    int node = gid >> 6;
    if (node >= N) return;
    int lane = threadIdx.x & 63;
    int sub = lane >> 3;   // edge slot 0..7
    int c8 = lane & 7;     // col octet (8 halfs = 16 B)
    int beg = offs[node], end = offs[node + 1];
    half8 acc0 = {};
    half8 acc1 = {};
    int j = beg + sub;
    for (; j + 8 < end; j += 16) {
        int s0 = esrc[j];
        int s1 = esrc[j + 8];
        half8 v0 = *(const half8*)(t + (size_t)s0 * 64 + c8 * 8);
        half8 v1 = *(const half8*)(t + (size_t)s1 * 64 + c8 * 8);
        acc0 += v0;   // 4x v_pk_add_f16
        acc1 += v1;
    }
    if (j < end) {
        int s0 = esrc[j];
        acc0 += *(const half8*)(t + (size_t)s0 * 64 + c8 * 8);
    }
    half8 acc = acc0 + acc1;
    float a[8];
#pragma unroll
    for (int k = 0; k < 8; ++k) a[k] = (float)acc[k];
#pragma unroll
    for (int k = 0; k < 8; ++k) {
        a[k] += __shfl_down(a[k], 32, 64);
        a[k] += __shfl_down(a[k], 16, 64);
        a[k] += __shfl_down(a[k], 8, 64);
    }
    if (sub == 0) {
        half8 hv;
#pragma unroll
        for (int k = 0; k < 8; ++k) {
            float v = a[k];
            if (bias != nullptr) v += bias[c8 * 8 + k];
            if (doRelu) v = fmaxf(v, 0.f);
            hv[k] = (_Float16)v;
        }
        *(half8*)(out + (size_t)node * 64 + c8 * 8) = hv;
    }
}

// ---------------- loss ----------------
__global__ void loss_pass(const float* __restrict__ rep, const int* __restrict__ labels, int N,
                          double* __restrict__ colSum, double* __restrict__ pickedSum,
                          int* __restrict__ cnt) {
    const int G = 8;
    const int ROWS = 512;
    int t = threadIdx.x;  // blockDim = 320
    int c = t % NCLS;
    int g = t / NCLS;
    int base = blockIdx.x * ROWS;
    int lim = min(base + ROWS, N);
    double sumLoc = 0.0, pickLoc = 0.0;
    int cntLoc = 0;
    for (int r = base + g; r < lim; r += G) {
        float v = rep[(size_t)r * NCLS + c];
        sumLoc += exp((double)v);
        if (labels[r] == c) { pickLoc += (double)v; cntLoc++; }
    }
    __shared__ double colP[G][NCLS];
    __shared__ int cntP[G][NCLS];
    __shared__ double waveP[5];
    colP[g][c] = sumLoc;
    cntP[g][c] = cntLoc;
    __syncthreads();
    if (g == 0) {
        double tot = 0.0;
        int ctot = 0;
        for (int gg = 0; gg < G; ++gg) { tot += colP[gg][c]; ctot += cntP[gg][c]; }
        atomicAdd(&colSum[c], tot);
        if (ctot) atomicAdd(&cnt[c], ctot);
    }
    double wv = pickLoc;
    for (int off = 32; off; off >>= 1) wv += __shfl_down(wv, off, 64);
    if ((t & 63) == 0) waveP[t >> 6] = wv;
    __syncthreads();
    if (t == 0) {
        double s = 0.0;
        for (int i = 0; i < 5; ++i) s += waveP[i];
        atomicAdd(pickedSum, s);
    }
}

__global__ void finalize_kernel(const double* __restrict__ colSum, const int* __restrict__ cnt,
                                const double* __restrict__ pickedSum, int N,
                                float* __restrict__ lossOut) {
    int t = threadIdx.x;
    double term = 0.0;
    if (t < NCLS) term = (double)cnt[t] * log(colSum[t]);
    for (int off = 32; off; off >>= 1) term += __shfl_down(term, off, 64);
    if (t == 0) lossOut[0] = (float)((term - pickedSum[0]) / (double)N);
}

extern "C" void kernel_launch(void* const* d_in, const int* in_sizes, int n_in,
                              void* d_out, int out_size, void* d_ws, size_t ws_size,
                              hipStream_t stream) {
    const float* features = (const float*)d_in[0];
    const float* W0 = (const float*)d_in[1];
    const float* b0 = (const float*)d_in[2];
    const float* W1 = (const float*)d_in[3];
    const float* b1 = (const float*)d_in[4];
    const float* W2 = (const float*)d_in[5];
    const float* b2 = (const float*)d_in[6];
    const int* src = (const int*)d_in[7];
    const int* dst = (const int*)d_in[8];
    const int* labels = (const int*)d_in[9];

    const int N = in_sizes[0] / 64;
    const int E = in_sizes[7];
    const int NC = in_sizes[6];  // 40

    char* ws = (char*)d_ws;
    size_t off = 0;
    auto alloc = [&](size_t bytes) -> void* {
        void* p = ws + off;
        off = (off + bytes + 255) & ~(size_t)255;
        return p;
    };
    int* offs      = (int*)alloc((size_t)(N + 1) * 4);
    int* esrc      = (int*)alloc((size_t)E * 4);
    _Float16* bufA = (_Float16*)alloc((size_t)N * 64 * 2);   // tmp / t0 / t1 / t2
    _Float16* bufB = (_Float16*)alloc((size_t)N * 64 * 2);   // h1 / h2
    int* blockHist = (int*)alloc((size_t)MAXB1 * MAXNB * 4);
    int* blockBase = (int*)alloc((size_t)MAXB1 * MAXNB * 4);
    int* bucketOffs= (int*)alloc((size_t)(MAXNB + 1) * 4);
    char* red      = (char*)alloc(512);
    double* colSum    = (double*)red;
    double* pickedSum = (double*)(red + 320);
    int* cntRed       = (int*)(red + 328);

    unsigned* tmp = (unsigned*)bufA;  // E*4 = 6.8 MB <= 12.8 MB; dead before gemm0

    float* rep = (float*)d_out;
    float* lossOut = rep + (size_t)N * NC;

    const int nb  = (N + 1023) >> 10;
    const int nB1 = (E + EPB - 1) / EPB;

    bucket_hist<<<nB1, 256, 0, stream>>>(dst, E, nb, blockHist);
    bucket_scan<<<1, 128, 0, stream>>>(blockHist, nB1, nb, blockBase, bucketOffs, offs, N, E,
                                       (int*)red);
    bucket_place<<<nB1, 256, 0, stream>>>(src, dst, E, nb, blockBase, tmp);
    bucket_finalize<<<nb, 512, 0, stream>>>(tmp, bucketOffs, N, offs, esrc);

    const int nodeWaveBlocks = (N * 64 + 255) / 256;  // one wave per node

    // layer 0: t0 = fp16(X@W0) ; h1 = fp16(relu(S@t0 + b0))
    gemm_fdot<<<2048, 256, 0, stream>>>(features, 0, W0, nullptr, bufA, 1, N, 64);
    agg64h_kernel<<<nodeWaveBlocks, 256, 0, stream>>>(bufA, offs, esrc, b0, bufB, N, 1);
    // layer 1: t1 = fp16(h1@W1) ; h2 = fp16(relu(S@t1 + b1))
    gemm_fdot<<<2048, 256, 0, stream>>>(bufB, 1, W1, nullptr, bufA, 1, N, 64);
    agg64h_kernel<<<nodeWaveBlocks, 256, 0, stream>>>(bufA, offs, esrc, b1, bufB, N, 1);
    // layer 2 (aggregate-first): t2 = fp16(S@h2) ; rep = t2@W2 + b2  [fp32]
    agg64h_kernel<<<nodeWaveBlocks, 256, 0, stream>>>(bufB, offs, esrc, nullptr, bufA, N, 0);
    gemm_fdot<<<2048, 256, 0, stream>>>(bufA, 1, W2, b2, rep, 0, N, NC);

    // loss
    loss_pass<<<(N + 511) / 512, 320, 0, stream>>>(rep, labels, N, colSum, pickedSum, cntRed);
    finalize_kernel<<<1, 64, 0, stream>>>(colSum, cntRed, pickedSum, N, lossOut);
}

// Round 10
// 400.625 us; speedup vs baseline: 1.0830x; 1.0830x over previous
//
#include <hip/hip_runtime.h>
#include <hip/hip_bf16.h>
#include <hip/hip_fp16.h>

#define NCLS 40

typedef __attribute__((ext_vector_type(8))) _Float16 half8;
typedef __attribute__((ext_vector_type(2))) _Float16 half2h;
union H2U { half2h h; unsigned u; };

// ---------------- CSR build: bucketed counting sort ----------------
#define EPB 16384     // edges per level-1 block
#define MAXB1 128     // max level-1 blocks (E <= MAXB1*EPB)
#define MAXNB 104     // max buckets (N <= MAXNB*1024)

__global__ void bucket_hist(const int* __restrict__ dst, int E, int nb,
                            int* __restrict__ blockHist) {
    __shared__ int cnt[4][MAXNB];
    int t = threadIdx.x;  // 256
    for (int i = t; i < 4 * MAXNB; i += 256) cnt[i / MAXNB][i % MAXNB] = 0;
    __syncthreads();
    int bk = t & 3;
    int base = blockIdx.x * EPB;
    int end = min(base + EPB, E);
    for (int i = base + t; i < end; i += 256) atomicAdd(&cnt[bk][dst[i] >> 10], 1);
    __syncthreads();
    for (int i = t; i < nb; i += 256)
        blockHist[blockIdx.x * nb + i] = cnt[0][i] + cnt[1][i] + cnt[2][i] + cnt[3][i];
}

// also zeroes the 512-byte reduction scratch (replaces a memset dispatch)
__global__ void bucket_scan(const int* __restrict__ blockHist, int nB1, int nb,
                            int* __restrict__ blockBase, int* __restrict__ bucketOffs,
                            int* __restrict__ offs, int N, int E, int* __restrict__ red32) {
    __shared__ int h[MAXB1 * MAXNB];
    __shared__ int btot[MAXNB];
    __shared__ int boffs[MAXNB + 1];
    int t = threadIdx.x;  // 128
    if (t < 128) red32[t] = 0;
    int total = nB1 * nb;
    for (int i = t; i < total; i += 128) h[i] = blockHist[i];
    __syncthreads();
    for (int b = t; b < nb; b += 128) {
        int run = 0;
        for (int i = 0; i < nB1; ++i) { int v = h[i * nb + b]; h[i * nb + b] = run; run += v; }
        btot[b] = run;
    }
    __syncthreads();
    if (t == 0) {
        int run = 0;
        for (int b = 0; b < nb; ++b) { boffs[b] = run; run += btot[b]; }
        boffs[nb] = run;
    }
    __syncthreads();
    for (int b = t; b < nb; b += 128) {
        int bo = boffs[b];
        for (int i = 0; i < nB1; ++i) h[i * nb + b] += bo;
    }
    __syncthreads();
    for (int i = t; i < total; i += 128) blockBase[i] = h[i];
    for (int b = t; b <= nb; b += 128) bucketOffs[b] = boffs[b];
    if (t == 0) offs[N] = E;
}

__global__ void bucket_place(const int* __restrict__ src, const int* __restrict__ dst, int E,
                             int nb, const int* __restrict__ blockBase,
                             unsigned* __restrict__ tmp) {
    __shared__ int cur[MAXNB];
    int t = threadIdx.x;  // 256
    for (int i = t; i < nb; i += 256) cur[i] = blockBase[blockIdx.x * nb + i];
    __syncthreads();
    int base = blockIdx.x * EPB;
    int end = min(base + EPB, E);
    for (int i = base + t; i < end; i += 256) {
        int d = dst[i];
        int s = src[i];
        unsigned pack = ((unsigned)(d & 1023) << 17) | (unsigned)s;  // src < 2^17
        int pos = atomicAdd(&cur[d >> 10], 1);
        tmp[pos] = pack;
    }
}

__global__ __launch_bounds__(512) void bucket_finalize(const unsigned* __restrict__ tmp,
                                                       const int* __restrict__ bucketOffs,
                                                       int N, int* __restrict__ offs,
                                                       int* __restrict__ esrc) {
    __shared__ int cnt[1024];
    __shared__ int wsum[8];
    int b = blockIdx.x;
    int t = threadIdx.x;  // 512
    int bstart = bucketOffs[b], bend = bucketOffs[b + 1];
    cnt[t] = 0;
    cnt[t + 512] = 0;
    __syncthreads();
    for (int i = bstart + t; i < bend; i += 512) atomicAdd(&cnt[tmp[i] >> 17], 1);
    __syncthreads();
    int c0 = cnt[2 * t], c1 = cnt[2 * t + 1];
    int s = c0 + c1;
    int lane = t & 63, w = t >> 6;
    int ssc = s;
    for (int off = 1; off < 64; off <<= 1) {
        int v = __shfl_up(ssc, off, 64);
        if (lane >= off) ssc += v;
    }
    if (lane == 63) wsum[w] = ssc;
    __syncthreads();
    int wo = 0;
#pragma unroll
    for (int k = 0; k < 8; ++k)
        if (k < w) wo += wsum[k];
    int excl = (ssc - s) + wo + bstart;
    __syncthreads();
    int node0 = (b << 10) + 2 * t;
    if (node0 < N) offs[node0] = excl;
    if (node0 + 1 < N) offs[node0 + 1] = excl + c0;
    cnt[2 * t] = excl;
    cnt[2 * t + 1] = excl + c0;
    __syncthreads();
    for (int i = bstart + t; i < bend; i += 512) {
        unsigned p = tmp[i];
        int pos = atomicAdd(&cnt[p >> 17], 1);
        esrc[pos] = (int)(p & 0x1FFFFu);
    }
}

// ---------------- dense X[N,64] @ W[64,FO] via packed fdot2 -----------------
__global__ __launch_bounds__(256) void gemm_fdot(const void* __restrict__ X, int xHalf,
                                                 const float* __restrict__ W,
                                                 const float* __restrict__ bias,
                                                 void* __restrict__ out, int outHalf,
                                                 int N, int FO) {
    int lane = threadIdx.x & 63;
    int waveId = (blockIdx.x * blockDim.x + threadIdx.x) >> 6;
    int nWaves = (gridDim.x * blockDim.x) >> 6;
    int cl = lane < FO ? lane : 0;
    int p = lane & 31;

    H2U wh[32];
#pragma unroll
    for (int j = 0; j < 32; ++j)
        wh[j].h = half2h{(_Float16)W[(2 * j) * FO + cl], (_Float16)W[(2 * j + 1) * FO + cl]};
    float gb = 0.f;
    if (bias != nullptr && lane < FO) gb = bias[lane];

    const unsigned* Xh = (const unsigned*)X;
    const float2* Xf = (const float2*)X;
    float* outF = (float*)out;
    _Float16* outH = (_Float16*)out;

    auto loadX = [&](int row) -> H2U {
        H2U r; r.u = 0;
        if (row < N) {
            if (xHalf) r.u = Xh[(size_t)row * 32 + p];
            else {
                float2 f = Xf[(size_t)row * 32 + p];
                r.h = half2h{(_Float16)f.x, (_Float16)f.y};
            }
        }
        return r;
    };

    int row = waveId;
    H2U xp = loadX(row);
    for (; row < N; row += nWaves) {
        H2U nxt = loadX(row + nWaves);
        float y0 = gb, y1 = 0.f;
#pragma unroll
        for (int j2 = 0; j2 < 32; j2 += 2) {
            H2U r0, r1;
            r0.u = __builtin_amdgcn_readlane(xp.u, j2);
            r1.u = __builtin_amdgcn_readlane(xp.u, j2 + 1);
            y0 = __builtin_amdgcn_fdot2(r0.h, wh[j2].h, y0, false);
            y1 = __builtin_amdgcn_fdot2(r1.h, wh[j2 + 1].h, y1, false);
        }
        float y = y0 + y1;
        if (lane < FO) {
            if (outHalf) outH[(size_t)row * FO + lane] = (_Float16)y;
            else         outF[(size_t)row * FO + lane] = y;
        }
        xp = nxt;
    }
}

// ---------------- aggregation over fp16 rows [N,64] (R6-proven form) --------
// one wave/node: 8 edge slots x 8 col-octets; fp32 cvt-accumulate, x2 unroll;
// bias + relu; fp16 out.
__global__ void agg64h_kernel(const _Float16* __restrict__ t, const int* __restrict__ offs,
                              const int* __restrict__ esrc, const float* __restrict__ bias,
                              _Float16* __restrict__ out, int N) {
    int gid = blockIdx.x * blockDim.x + threadIdx.x;
    int node = gid >> 6;
    if (node >= N) return;
    int lane = threadIdx.x & 63;
    int sub = lane >> 3;   // edge slot 0..7
    int c8 = lane & 7;     // col octet (8 halfs = 16 B)
    int beg = offs[node], end = offs[node + 1];
    float a[8];
#pragma unroll
    for (int k = 0; k < 8; ++k) a[k] = 0.f;
    int j = beg + sub;
    for (; j + 8 < end; j += 16) {
        int s0 = esrc[j];
        int s1 = esrc[j + 8];
        half8 v0 = *(const half8*)(t + (size_t)s0 * 64 + c8 * 8);
        half8 v1 = *(const half8*)(t + (size_t)s1 * 64 + c8 * 8);
#pragma unroll
        for (int k = 0; k < 8; ++k) a[k] += (float)v0[k] + (float)v1[k];
    }
    if (j < end) {
        int s0 = esrc[j];
        half8 v0 = *(const half8*)(t + (size_t)s0 * 64 + c8 * 8);
#pragma unroll
        for (int k = 0; k < 8; ++k) a[k] += (float)v0[k];
    }
#pragma unroll
    for (int k = 0; k < 8; ++k) {
        a[k] += __shfl_down(a[k], 32, 64);
        a[k] += __shfl_down(a[k], 16, 64);
        a[k] += __shfl_down(a[k], 8, 64);
    }
    if (sub == 0) {
        half8 hv;
#pragma unroll
        for (int k = 0; k < 8; ++k) {
            float v = fmaxf(a[k] + bias[c8 * 8 + k], 0.f);  // bias + relu
            hv[k] = (_Float16)v;
        }
        *(half8*)(out + (size_t)node * 64 + c8 * 8) = hv;
    }
}

// ---------------- final-layer aggregation over tight fp16 rows [N,40] -------
// u rows are 40 halfs = 80 B (16B-aligned). 8 edge slots x octets 0..4 active;
// octets 5..7 idle (lane-stable predicate). fp32 out with bias, no relu.
__global__ void agg40h_kernel(const _Float16* __restrict__ u, const int* __restrict__ offs,
                              const int* __restrict__ esrc, const float* __restrict__ bias,
                              float* __restrict__ rep, int N) {
    int gid = blockIdx.x * blockDim.x + threadIdx.x;
    int node = gid >> 6;
    if (node >= N) return;
    int lane = threadIdx.x & 63;
    int sub = lane >> 3;   // edge slot 0..7
    int c8 = lane & 7;     // col octet; active 0..4
    int beg = offs[node], end = offs[node + 1];
    float a[8];
#pragma unroll
    for (int k = 0; k < 8; ++k) a[k] = 0.f;
    if (c8 < 5) {
        int j = beg + sub;
        for (; j + 8 < end; j += 16) {
            int s0 = esrc[j];
            int s1 = esrc[j + 8];
            half8 v0 = *(const half8*)(u + (size_t)s0 * 40 + c8 * 8);
            half8 v1 = *(const half8*)(u + (size_t)s1 * 40 + c8 * 8);
#pragma unroll
            for (int k = 0; k < 8; ++k) a[k] += (float)v0[k] + (float)v1[k];
        }
        if (j < end) {
            int s0 = esrc[j];
            half8 v0 = *(const half8*)(u + (size_t)s0 * 40 + c8 * 8);
#pragma unroll
            for (int k = 0; k < 8; ++k) a[k] += (float)v0[k];
        }
    }
#pragma unroll
    for (int k = 0; k < 8; ++k) {
        a[k] += __shfl_down(a[k], 32, 64);
        a[k] += __shfl_down(a[k], 16, 64);
        a[k] += __shfl_down(a[k], 8, 64);
    }
    if (sub == 0 && c8 < 5) {
        float* po = rep + (size_t)node * NCLS + c8 * 8;
        float4 r0, r1;
        r0.x = a[0] + bias[c8 * 8 + 0]; r0.y = a[1] + bias[c8 * 8 + 1];
        r0.z = a[2] + bias[c8 * 8 + 2]; r0.w = a[3] + bias[c8 * 8 + 3];
        r1.x = a[4] + bias[c8 * 8 + 4]; r1.y = a[5] + bias[c8 * 8 + 5];
        r1.z = a[6] + bias[c8 * 8 + 6]; r1.w = a[7] + bias[c8 * 8 + 7];
        *(float4*)(po) = r0;
        *(float4*)(po + 4) = r1;
    }
}

// ---------------- loss ----------------
__global__ void loss_pass(const float* __restrict__ rep, const int* __restrict__ labels, int N,
                          double* __restrict__ colSum, double* __restrict__ pickedSum,
                          int* __restrict__ cnt) {
    const int G = 8;
    const int ROWS = 512;
    int t = threadIdx.x;  // blockDim = 320
    int c = t % NCLS;
    int g = t / NCLS;
    int base = blockIdx.x * ROWS;
    int lim = min(base + ROWS, N);
    double sumLoc = 0.0, pickLoc = 0.0;
    int cntLoc = 0;
    for (int r = base + g; r < lim; r += G) {
        float v = rep[(size_t)r * NCLS + c];
        sumLoc += exp((double)v);
        if (labels[r] == c) { pickLoc += (double)v; cntLoc++; }
    }
    __shared__ double colP[G][NCLS];
    __shared__ int cntP[G][NCLS];
    __shared__ double waveP[5];
    colP[g][c] = sumLoc;
    cntP[g][c] = cntLoc;
    __syncthreads();
    if (g == 0) {
        double tot = 0.0;
        int ctot = 0;
        for (int gg = 0; gg < G; ++gg) { tot += colP[gg][c]; ctot += cntP[gg][c]; }
        atomicAdd(&colSum[c], tot);
        if (ctot) atomicAdd(&cnt[c], ctot);
    }
    double wv = pickLoc;
    for (int off = 32; off; off >>= 1) wv += __shfl_down(wv, off, 64);
    if ((t & 63) == 0) waveP[t >> 6] = wv;
    __syncthreads();
    if (t == 0) {
        double s = 0.0;
        for (int i = 0; i < 5; ++i) s += waveP[i];
        atomicAdd(pickedSum, s);
    }
}

__global__ void finalize_kernel(const double* __restrict__ colSum, const int* __restrict__ cnt,
                                const double* __restrict__ pickedSum, int N,
                                float* __restrict__ lossOut) {
    int t = threadIdx.x;
    double term = 0.0;
    if (t < NCLS) term = (double)cnt[t] * log(colSum[t]);
    for (int off = 32; off; off >>= 1) term += __shfl_down(term, off, 64);
    if (t == 0) lossOut[0] = (float)((term - pickedSum[0]) / (double)N);
}

extern "C" void kernel_launch(void* const* d_in, const int* in_sizes, int n_in,
                              void* d_out, int out_size, void* d_ws, size_t ws_size,
                              hipStream_t stream) {
    const float* features = (const float*)d_in[0];
    const float* W0 = (const float*)d_in[1];
    const float* b0 = (const float*)d_in[2];
    const float* W1 = (const float*)d_in[3];
    const float* b1 = (const float*)d_in[4];
    const float* W2 = (const float*)d_in[5];
    const float* b2 = (const float*)d_in[6];
    const int* src = (const int*)d_in[7];
    const int* dst = (const int*)d_in[8];
    const int* labels = (const int*)d_in[9];

    const int N = in_sizes[0] / 64;
    const int E = in_sizes[7];
    const int NC = in_sizes[6];  // 40

    char* ws = (char*)d_ws;
    size_t off = 0;
    auto alloc = [&](size_t bytes) -> void* {
        void* p = ws + off;
        off = (off + bytes + 255) & ~(size_t)255;
        return p;
    };
    int* offs      = (int*)alloc((size_t)(N + 1) * 4);
    int* esrc      = (int*)alloc((size_t)E * 4);
    _Float16* bufA = (_Float16*)alloc((size_t)N * 64 * 2);   // tmp / t0 / t1 / u
    _Float16* bufB = (_Float16*)alloc((size_t)N * 64 * 2);   // h1 / h2
    int* blockHist = (int*)alloc((size_t)MAXB1 * MAXNB * 4);
    int* blockBase = (int*)alloc((size_t)MAXB1 * MAXNB * 4);
    int* bucketOffs= (int*)alloc((size_t)(MAXNB + 1) * 4);
    char* red      = (char*)alloc(512);
    double* colSum    = (double*)red;
    double* pickedSum = (double*)(red + 320);
    int* cntRed       = (int*)(red + 328);

    unsigned* tmp = (unsigned*)bufA;  // E*4 = 6.8 MB <= 12.8 MB; dead before gemm0

    float* rep = (float*)d_out;
    float* lossOut = rep + (size_t)N * NC;

    const int nb  = (N + 1023) >> 10;
    const int nB1 = (E + EPB - 1) / EPB;

    bucket_hist<<<nB1, 256, 0, stream>>>(dst, E, nb, blockHist);
    bucket_scan<<<1, 128, 0, stream>>>(blockHist, nB1, nb, blockBase, bucketOffs, offs, N, E,
                                       (int*)red);
    bucket_place<<<nB1, 256, 0, stream>>>(src, dst, E, nb, blockBase, tmp);
    bucket_finalize<<<nb, 512, 0, stream>>>(tmp, bucketOffs, N, offs, esrc);

    const int nodeWaveBlocks = (N * 64 + 255) / 256;  // one wave per node

    // layer 0: t0 = fp16(X@W0) ; h1 = fp16(relu(S@t0 + b0))
    gemm_fdot<<<2048, 256, 0, stream>>>(features, 0, W0, nullptr, bufA, 1, N, 64);
    agg64h_kernel<<<nodeWaveBlocks, 256, 0, stream>>>(bufA, offs, esrc, b0, bufB, N);
    // layer 1: t1 = fp16(h1@W1) ; h2 = fp16(relu(S@t1 + b1))
    gemm_fdot<<<2048, 256, 0, stream>>>(bufB, 1, W1, nullptr, bufA, 1, N, 64);
    agg64h_kernel<<<nodeWaveBlocks, 256, 0, stream>>>(bufA, offs, esrc, b1, bufB, N);
    // layer 2 (gather-second, tight 40-wide): u = fp16(h2@W2) ; rep = S@u + b2
    gemm_fdot<<<2048, 256, 0, stream>>>(bufB, 1, W2, nullptr, bufA, 1, N, NC);
    agg40h_kernel<<<nodeWaveBlocks, 256, 0, stream>>>(bufA, offs, esrc, b2, rep, N);

    // loss
    loss_pass<<<(N + 511) / 512, 320, 0, stream>>>(rep, labels, N, colSum, pickedSum, cntRed);
    finalize_kernel<<<1, 64, 0, stream>>>(colSum, cntRed, pickedSum, N, lossOut);
}

// Round 11
// 379.509 us; speedup vs baseline: 1.1432x; 1.0556x over previous
//
#include <hip/hip_runtime.h>
#include <hip/hip_bf16.h>
#include <hip/hip_fp16.h>

#define NCLS 40

typedef __attribute__((ext_vector_type(8))) _Float16 half8;
typedef __attribute__((ext_vector_type(2))) _Float16 half2h;
union H2U { half2h h; unsigned u; };

// ---------------- CSR build: bucketed counting sort ----------------
#define EPB 16384     // edges per level-1 block
#define MAXB1 128     // max level-1 blocks (E <= MAXB1*EPB)
#define MAXNB 104     // max buckets (N <= MAXNB*1024)

// Fused: blocks [0,nB1) do the edge histogram; blocks [nB1,..) do gemm0
// (X fp32 [N,64] @ W0 -> fp16 out). Independent work, complementary pipes.
__global__ __launch_bounds__(256) void hist_and_gemm(
        const int* __restrict__ dst, int E, int nb, int* __restrict__ blockHist, int nB1,
        const float* __restrict__ X, const float* __restrict__ W,
        _Float16* __restrict__ out, int N) {
    __shared__ int cnt[4][MAXNB];
    int t = threadIdx.x;  // 256
    if ((int)blockIdx.x < nB1) {
        for (int i = t; i < 4 * MAXNB; i += 256) cnt[i / MAXNB][i % MAXNB] = 0;
        __syncthreads();
        int bk = t & 3;
        int base = blockIdx.x * EPB;
        int end = min(base + EPB, E);
        for (int i = base + t; i < end; i += 256) atomicAdd(&cnt[bk][dst[i] >> 10], 1);
        __syncthreads();
        for (int i = t; i < nb; i += 256)
            blockHist[blockIdx.x * nb + i] = cnt[0][i] + cnt[1][i] + cnt[2][i] + cnt[3][i];
        return;
    }
    // ---- gemm0 part ----
    int bid = blockIdx.x - nB1;
    int nBlocks = gridDim.x - nB1;
    int lane = t & 63;
    int waveId = (bid * 256 + t) >> 6;
    int nWaves = (nBlocks * 256) >> 6;
    int p = lane & 31;

    H2U wh[32];
#pragma unroll
    for (int j = 0; j < 32; ++j)
        wh[j].h = half2h{(_Float16)W[(2 * j) * 64 + lane], (_Float16)W[(2 * j + 1) * 64 + lane]};

    const float2* Xf = (const float2*)X;
    auto loadX = [&](int row) -> H2U {
        H2U r; r.u = 0;
        if (row < N) {
            float2 f = Xf[(size_t)row * 32 + p];
            r.h = half2h{(_Float16)f.x, (_Float16)f.y};
        }
        return r;
    };
    int row = waveId;
    H2U xp = loadX(row);
    for (; row < N; row += nWaves) {
        H2U nxt = loadX(row + nWaves);
        float y0 = 0.f, y1 = 0.f;
#pragma unroll
        for (int j2 = 0; j2 < 32; j2 += 2) {
            H2U r0, r1;
            r0.u = __builtin_amdgcn_readlane(xp.u, j2);
            r1.u = __builtin_amdgcn_readlane(xp.u, j2 + 1);
            y0 = __builtin_amdgcn_fdot2(r0.h, wh[j2].h, y0, false);
            y1 = __builtin_amdgcn_fdot2(r1.h, wh[j2 + 1].h, y1, false);
        }
        out[(size_t)row * 64 + lane] = (_Float16)(y0 + y1);
        xp = nxt;
    }
}

// also zeroes the 512-byte reduction scratch (replaces a memset dispatch)
__global__ void bucket_scan(const int* __restrict__ blockHist, int nB1, int nb,
                            int* __restrict__ blockBase, int* __restrict__ bucketOffs,
                            int* __restrict__ offs, int N, int E, int* __restrict__ red32) {
    __shared__ int h[MAXB1 * MAXNB];
    __shared__ int btot[MAXNB];
    __shared__ int boffs[MAXNB + 1];
    int t = threadIdx.x;  // 128
    if (t < 128) red32[t] = 0;
    int total = nB1 * nb;
    for (int i = t; i < total; i += 128) h[i] = blockHist[i];
    __syncthreads();
    for (int b = t; b < nb; b += 128) {
        int run = 0;
        for (int i = 0; i < nB1; ++i) { int v = h[i * nb + b]; h[i * nb + b] = run; run += v; }
        btot[b] = run;
    }
    __syncthreads();
    if (t == 0) {
        int run = 0;
        for (int b = 0; b < nb; ++b) { boffs[b] = run; run += btot[b]; }
        boffs[nb] = run;
    }
    __syncthreads();
    for (int b = t; b < nb; b += 128) {
        int bo = boffs[b];
        for (int i = 0; i < nB1; ++i) h[i * nb + b] += bo;
    }
    __syncthreads();
    for (int i = t; i < total; i += 128) blockBase[i] = h[i];
    for (int b = t; b <= nb; b += 128) bucketOffs[b] = boffs[b];
    if (t == 0) offs[N] = E;
}

__global__ void bucket_place(const int* __restrict__ src, const int* __restrict__ dst, int E,
                             int nb, const int* __restrict__ blockBase,
                             unsigned* __restrict__ tmp) {
    __shared__ int cur[MAXNB];
    int t = threadIdx.x;  // 256
    for (int i = t; i < nb; i += 256) cur[i] = blockBase[blockIdx.x * nb + i];
    __syncthreads();
    int base = blockIdx.x * EPB;
    int end = min(base + EPB, E);
    for (int i = base + t; i < end; i += 256) {
        int d = dst[i];
        int s = src[i];
        unsigned pack = ((unsigned)(d & 1023) << 17) | (unsigned)s;  // src < 2^17
        int pos = atomicAdd(&cur[d >> 10], 1);
        tmp[pos] = pack;
    }
}

__global__ __launch_bounds__(512) void bucket_finalize(const unsigned* __restrict__ tmp,
                                                       const int* __restrict__ bucketOffs,
                                                       int N, int* __restrict__ offs,
                                                       int* __restrict__ esrc) {
    __shared__ int cnt[1024];
    __shared__ int wsum[8];
    int b = blockIdx.x;
    int t = threadIdx.x;  // 512
    int bstart = bucketOffs[b], bend = bucketOffs[b + 1];
    cnt[t] = 0;
    cnt[t + 512] = 0;
    __syncthreads();
    for (int i = bstart + t; i < bend; i += 512) atomicAdd(&cnt[tmp[i] >> 17], 1);
    __syncthreads();
    int c0 = cnt[2 * t], c1 = cnt[2 * t + 1];
    int s = c0 + c1;
    int lane = t & 63, w = t >> 6;
    int ssc = s;
    for (int off = 1; off < 64; off <<= 1) {
        int v = __shfl_up(ssc, off, 64);
        if (lane >= off) ssc += v;
    }
    if (lane == 63) wsum[w] = ssc;
    __syncthreads();
    int wo = 0;
#pragma unroll
    for (int k = 0; k < 8; ++k)
        if (k < w) wo += wsum[k];
    int excl = (ssc - s) + wo + bstart;
    __syncthreads();
    int node0 = (b << 10) + 2 * t;
    if (node0 < N) offs[node0] = excl;
    if (node0 + 1 < N) offs[node0 + 1] = excl + c0;
    cnt[2 * t] = excl;
    cnt[2 * t + 1] = excl + c0;
    __syncthreads();
    for (int i = bstart + t; i < bend; i += 512) {
        unsigned p = tmp[i];
        int pos = atomicAdd(&cnt[p >> 17], 1);
        esrc[pos] = (int)(p & 0x1FFFFu);
    }
}

// ---------------- dense X[N,64] @ W[64,FO] via packed fdot2 -----------------
__global__ __launch_bounds__(256) void gemm_fdot(const void* __restrict__ X, int xHalf,
                                                 const float* __restrict__ W,
                                                 const float* __restrict__ bias,
                                                 void* __restrict__ out, int outHalf,
                                                 int N, int FO) {
    int lane = threadIdx.x & 63;
    int waveId = (blockIdx.x * blockDim.x + threadIdx.x) >> 6;
    int nWaves = (gridDim.x * blockDim.x) >> 6;
    int cl = lane < FO ? lane : 0;
    int p = lane & 31;

    H2U wh[32];
#pragma unroll
    for (int j = 0; j < 32; ++j)
        wh[j].h = half2h{(_Float16)W[(2 * j) * FO + cl], (_Float16)W[(2 * j + 1) * FO + cl]};
    float gb = 0.f;
    if (bias != nullptr && lane < FO) gb = bias[lane];

    const unsigned* Xh = (const unsigned*)X;
    const float2* Xf = (const float2*)X;
    float* outF = (float*)out;
    _Float16* outH = (_Float16*)out;

    auto loadX = [&](int row) -> H2U {
        H2U r; r.u = 0;
        if (row < N) {
            if (xHalf) r.u = Xh[(size_t)row * 32 + p];
            else {
                float2 f = Xf[(size_t)row * 32 + p];
                r.h = half2h{(_Float16)f.x, (_Float16)f.y};
            }
        }
        return r;
    };

    int row = waveId;
    H2U xp = loadX(row);
    for (; row < N; row += nWaves) {
        H2U nxt = loadX(row + nWaves);
        float y0 = gb, y1 = 0.f;
#pragma unroll
        for (int j2 = 0; j2 < 32; j2 += 2) {
            H2U r0, r1;
            r0.u = __builtin_amdgcn_readlane(xp.u, j2);
            r1.u = __builtin_amdgcn_readlane(xp.u, j2 + 1);
            y0 = __builtin_amdgcn_fdot2(r0.h, wh[j2].h, y0, false);
            y1 = __builtin_amdgcn_fdot2(r1.h, wh[j2 + 1].h, y1, false);
        }
        float y = y0 + y1;
        if (lane < FO) {
            if (outHalf) outH[(size_t)row * FO + lane] = (_Float16)y;
            else         outF[(size_t)row * FO + lane] = y;
        }
        xp = nxt;
    }
}

// fdot2-selector accumulate: a_even += v.lo, a_odd += v.hi (exact: x*1.0, fp32 acc)
#define ACC_PAIR(word, ae, ao)                                        \
    do {                                                              \
        H2U _p; _p.u = (word);                                        \
        (ae) = __builtin_amdgcn_fdot2(_p.h, selE.h, (ae), false);     \
        (ao) = __builtin_amdgcn_fdot2(_p.h, selO.h, (ao), false);     \
    } while (0)

// ---------------- aggregation over fp16 rows [N,64] -------------------------
// one wave/node: 8 edge slots x 8 col-octets; fdot2 accumulate (8 VOP3P per
// 16 B load), fp32 cross-sub shuffle reduce; bias + relu; fp16 out.
__global__ void agg64h_kernel(const _Float16* __restrict__ t, const int* __restrict__ offs,
                              const int* __restrict__ esrc, const float* __restrict__ bias,
                              _Float16* __restrict__ out, int N) {
    int gid = blockIdx.x * blockDim.x + threadIdx.x;
    int node = gid >> 6;
    if (node >= N) return;
    int lane = threadIdx.x & 63;
    int sub = lane >> 3;   // edge slot 0..7
    int c8 = lane & 7;     // col octet (8 halfs = 16 B)
    int beg = offs[node], end = offs[node + 1];
    H2U selE, selO;
    selE.h = half2h{(_Float16)1.f, (_Float16)0.f};
    selO.h = half2h{(_Float16)0.f, (_Float16)1.f};
    float a[8];
#pragma unroll
    for (int k = 0; k < 8; ++k) a[k] = 0.f;
    int j = beg + sub;
    for (; j + 8 < end; j += 16) {
        int s0 = esrc[j];
        int s1 = esrc[j + 8];
        uint4 v0 = *(const uint4*)(t + (size_t)s0 * 64 + c8 * 8);
        uint4 v1 = *(const uint4*)(t + (size_t)s1 * 64 + c8 * 8);
        ACC_PAIR(v0.x, a[0], a[1]); ACC_PAIR(v0.y, a[2], a[3]);
        ACC_PAIR(v0.z, a[4], a[5]); ACC_PAIR(v0.w, a[6], a[7]);
        ACC_PAIR(v1.x, a[0], a[1]); ACC_PAIR(v1.y, a[2], a[3]);
        ACC_PAIR(v1.z, a[4], a[5]); ACC_PAIR(v1.w, a[6], a[7]);
    }
    if (j < end) {
        int s0 = esrc[j];
        uint4 v0 = *(const uint4*)(t + (size_t)s0 * 64 + c8 * 8);
        ACC_PAIR(v0.x, a[0], a[1]); ACC_PAIR(v0.y, a[2], a[3]);
        ACC_PAIR(v0.z, a[4], a[5]); ACC_PAIR(v0.w, a[6], a[7]);
    }
#pragma unroll
    for (int k = 0; k < 8; ++k) {
        a[k] += __shfl_down(a[k], 32, 64);
        a[k] += __shfl_down(a[k], 16, 64);
        a[k] += __shfl_down(a[k], 8, 64);
    }
    if (sub == 0) {
        half8 hv;
#pragma unroll
        for (int k = 0; k < 8; ++k) {
            float v = fmaxf(a[k] + bias[c8 * 8 + k], 0.f);  // bias + relu
            hv[k] = (_Float16)v;
        }
        *(half8*)(out + (size_t)node * 64 + c8 * 8) = hv;
    }
}

// ---------------- final-layer aggregation over tight fp16 rows [N,40] -------
__global__ void agg40h_kernel(const _Float16* __restrict__ u, const int* __restrict__ offs,
                              const int* __restrict__ esrc, const float* __restrict__ bias,
                              float* __restrict__ rep, int N) {
    int gid = blockIdx.x * blockDim.x + threadIdx.x;
    int node = gid >> 6;
    if (node >= N) return;
    int lane = threadIdx.x & 63;
    int sub = lane >> 3;   // edge slot 0..7
    int c8 = lane & 7;     // col octet; active 0..4
    int beg = offs[node], end = offs[node + 1];
    H2U selE, selO;
    selE.h = half2h{(_Float16)1.f, (_Float16)0.f};
    selO.h = half2h{(_Float16)0.f, (_Float16)1.f};
    float a[8];
#pragma unroll
    for (int k = 0; k < 8; ++k) a[k] = 0.f;
    if (c8 < 5) {
        int j = beg + sub;
        for (; j + 8 < end; j += 16) {
            int s0 = esrc[j];
            int s1 = esrc[j + 8];
            uint4 v0 = *(const uint4*)(u + (size_t)s0 * 40 + c8 * 8);
            uint4 v1 = *(const uint4*)(u + (size_t)s1 * 40 + c8 * 8);
            ACC_PAIR(v0.x, a[0], a[1]); ACC_PAIR(v0.y, a[2], a[3]);
            ACC_PAIR(v0.z, a[4], a[5]); ACC_PAIR(v0.w, a[6], a[7]);
            ACC_PAIR(v1.x, a[0], a[1]); ACC_PAIR(v1.y, a[2], a[3]);
            ACC_PAIR(v1.z, a[4], a[5]); ACC_PAIR(v1.w, a[6], a[7]);
        }
        if (j < end) {
            int s0 = esrc[j];
            uint4 v0 = *(const uint4*)(u + (size_t)s0 * 40 + c8 * 8);
            ACC_PAIR(v0.x, a[0], a[1]); ACC_PAIR(v0.y, a[2], a[3]);
            ACC_PAIR(v0.z, a[4], a[5]); ACC_PAIR(v0.w, a[6], a[7]);
        }
    }
#pragma unroll
    for (int k = 0; k < 8; ++k) {
        a[k] += __shfl_down(a[k], 32, 64);
        a[k] += __shfl_down(a[k], 16, 64);
        a[k] += __shfl_down(a[k], 8, 64);
    }
    if (sub == 0 && c8 < 5) {
        float* po = rep + (size_t)node * NCLS + c8 * 8;
        float4 r0, r1;
        r0.x = a[0] + bias[c8 * 8 + 0]; r0.y = a[1] + bias[c8 * 8 + 1];
        r0.z = a[2] + bias[c8 * 8 + 2]; r0.w = a[3] + bias[c8 * 8 + 3];
        r1.x = a[4] + bias[c8 * 8 + 4]; r1.y = a[5] + bias[c8 * 8 + 5];
        r1.z = a[6] + bias[c8 * 8 + 6]; r1.w = a[7] + bias[c8 * 8 + 7];
        *(float4*)(po) = r0;
        *(float4*)(po + 4) = r1;
    }
}

// ---------------- loss ----------------
__global__ void loss_pass(const float* __restrict__ rep, const int* __restrict__ labels, int N,
                          double* __restrict__ colSum, double* __restrict__ pickedSum,
                          int* __restrict__ cnt) {
    const int G = 8;
    const int ROWS = 512;
    int t = threadIdx.x;  // blockDim = 320
    int c = t % NCLS;
    int g = t / NCLS;
    int base = blockIdx.x * ROWS;
    int lim = min(base + ROWS, N);
    double sumLoc = 0.0, pickLoc = 0.0;
    int cntLoc = 0;
    for (int r = base + g; r < lim; r += G) {
        float v = rep[(size_t)r * NCLS + c];
        sumLoc += exp((double)v);
        if (labels[r] == c) { pickLoc += (double)v; cntLoc++; }
    }
    __shared__ double colP[G][NCLS];
    __shared__ int cntP[G][NCLS];
    __shared__ double waveP[5];
    colP[g][c] = sumLoc;
    cntP[g][c] = cntLoc;
    __syncthreads();
    if (g == 0) {
        double tot = 0.0;
        int ctot = 0;
        for (int gg = 0; gg < G; ++gg) { tot += colP[gg][c]; ctot += cntP[gg][c]; }
        atomicAdd(&colSum[c], tot);
        if (ctot) atomicAdd(&cnt[c], ctot);
    }
    double wv = pickLoc;
    for (int off = 32; off; off >>= 1) wv += __shfl_down(wv, off, 64);
    if ((t & 63) == 0) waveP[t >> 6] = wv;
    __syncthreads();
    if (t == 0) {
        double s = 0.0;
        for (int i = 0; i < 5; ++i) s += waveP[i];
        atomicAdd(pickedSum, s);
    }
}

__global__ void finalize_kernel(const double* __restrict__ colSum, const int* __restrict__ cnt,
                                const double* __restrict__ pickedSum, int N,
                                float* __restrict__ lossOut) {
    int t = threadIdx.x;
    double term = 0.0;
    if (t < NCLS) term = (double)cnt[t] * log(colSum[t]);
    for (int off = 32; off; off >>= 1) term += __shfl_down(term, off, 64);
    if (t == 0) lossOut[0] = (float)((term - pickedSum[0]) / (double)N);
}

extern "C" void kernel_launch(void* const* d_in, const int* in_sizes, int n_in,
                              void* d_out, int out_size, void* d_ws, size_t ws_size,
                              hipStream_t stream) {
    const float* features = (const float*)d_in[0];
    const float* W0 = (const float*)d_in[1];
    const float* b0 = (const float*)d_in[2];
    const float* W1 = (const float*)d_in[3];
    const float* b1 = (const float*)d_in[4];
    const float* W2 = (const float*)d_in[5];
    const float* b2 = (const float*)d_in[6];
    const int* src = (const int*)d_in[7];
    const int* dst = (const int*)d_in[8];
    const int* labels = (const int*)d_in[9];

    const int N = in_sizes[0] / 64;
    const int E = in_sizes[7];
    const int NC = in_sizes[6];  // 40

    char* ws = (char*)d_ws;
    size_t off = 0;
    auto alloc = [&](size_t bytes) -> void* {
        void* p = ws + off;
        off = (off + bytes + 255) & ~(size_t)255;
        return p;
    };
    int* offs      = (int*)alloc((size_t)(N + 1) * 4);
    int* esrc      = (int*)alloc((size_t)E * 4);
    _Float16* bufA = (_Float16*)alloc((size_t)N * 64 * 2);   // tmp-alias is separate now
    _Float16* bufB = (_Float16*)alloc((size_t)N * 64 * 2);   // h1 / h2
    unsigned* tmp  = (unsigned*)alloc((size_t)E * 4);        // packed edges (hist+gemm overlap
                                                             // means bufA is no longer dead)
    int* blockHist = (int*)alloc((size_t)MAXB1 * MAXNB * 4);
    int* blockBase = (int*)alloc((size_t)MAXB1 * MAXNB * 4);
    int* bucketOffs= (int*)alloc((size_t)(MAXNB + 1) * 4);
    char* red      = (char*)alloc(512);
    double* colSum    = (double*)red;
    double* pickedSum = (double*)(red + 320);
    int* cntRed       = (int*)(red + 328);

    float* rep = (float*)d_out;
    float* lossOut = rep + (size_t)N * NC;

    const int nb  = (N + 1023) >> 10;
    const int nB1 = (E + EPB - 1) / EPB;

    // fused: edge histogram + gemm0 (t0 = fp16(X@W0)) in one dispatch
    hist_and_gemm<<<nB1 + 2048, 256, 0, stream>>>(dst, E, nb, blockHist, nB1,
                                                  features, W0, bufA, N);
    bucket_scan<<<1, 128, 0, stream>>>(blockHist, nB1, nb, blockBase, bucketOffs, offs, N, E,
                                       (int*)red);
    bucket_place<<<nB1, 256, 0, stream>>>(src, dst, E, nb, blockBase, tmp);
    bucket_finalize<<<nb, 512, 0, stream>>>(tmp, bucketOffs, N, offs, esrc);

    const int nodeWaveBlocks = (N * 64 + 255) / 256;  // one wave per node

    // layer 0: h1 = fp16(relu(S@t0 + b0))
    agg64h_kernel<<<nodeWaveBlocks, 256, 0, stream>>>(bufA, offs, esrc, b0, bufB, N);
    // layer 1: t1 = fp16(h1@W1) ; h2 = fp16(relu(S@t1 + b1))
    gemm_fdot<<<2048, 256, 0, stream>>>(bufB, 1, W1, nullptr, bufA, 1, N, 64);
    agg64h_kernel<<<nodeWaveBlocks, 256, 0, stream>>>(bufA, offs, esrc, b1, bufB, N);
    // layer 2 (gather-second, tight 40-wide): u = fp16(h2@W2) ; rep = S@u + b2
    gemm_fdot<<<2048, 256, 0, stream>>>(bufB, 1, W2, nullptr, bufA, 1, N, NC);
    agg40h_kernel<<<nodeWaveBlocks, 256, 0, stream>>>(bufA, offs, esrc, b2, rep, N);

    // loss
    loss_pass<<<(N + 511) / 512, 320, 0, stream>>>(rep, labels, N, colSum, pickedSum, cntRed);
    finalize_kernel<<<1, 64, 0, stream>>>(colSum, cntRed, pickedSum, N, lossOut);
}